// Round 13
// baseline (2037.616 us; speedup 1.0000x reference)
//
#include <hip/hip_runtime.h>
#include <math.h>

#define HDIM    2048
#define TSTEPS  256
#define BBASIS  8
#define RING_D  4
#define GRP     32          // scan group: 32 blocks on ONE XCD
#define NR      8           // fallback: replicas per slot
#define FCAP    3000u       // formation spin cap (iterations)
#define PCAP    4096u       // data-poll spin cap (iterations)

typedef float    f32x4 __attribute__((ext_vector_type(4)));
typedef unsigned u32x2 __attribute__((ext_vector_type(2)));

// ---- L2-scope ops (sc0: bypass L1, hit this XCD's L2; no sc1) ----
__device__ inline void store_l2_f4(float* p, f32x4 v) {
    asm volatile("global_store_dwordx4 %0, %1, off sc0"
                 :: "v"(p), "v"(v) : "memory");
}
__device__ inline f32x4 load_l2_f4(const float* p) {
    f32x4 a;
    asm volatile("global_load_dwordx4 %0, %1, off sc0\n\t"
                 "s_waitcnt vmcnt(0)"
                 : "=&v"(a) : "v"(p) : "memory");
    return a;
}
// ---- MALL-coherent ops (cross-XCD) ----
__device__ inline void store_coherent_f4(float* p, f32x4 v) {
    asm volatile("global_store_dwordx4 %0, %1, off sc0 sc1"
                 :: "v"(p), "v"(v) : "memory");
}
__device__ inline f32x4 load_coherent_f4(const float* p) {
    f32x4 a;
    asm volatile("global_load_dwordx4 %0, %1, off sc0 sc1\n\t"
                 "s_waitcnt vmcnt(0)"
                 : "=&v"(a) : "v"(p) : "memory");
    return a;
}

__device__ inline unsigned bf16rne(float f) {   // round-to-nearest-even bf16
    unsigned b = __float_as_uint(f);
    return (b + 0x7FFFu + ((b >> 16) & 1u)) >> 16;
}

// =====================================================================
// PREP: 256 blocks x 256 threads. ub_g[2048][1024] = u packed bf16 pairs;
// ig_g[256][2048] f32. Kernel-boundary flush publishes both.
// =====================================================================
__global__ __launch_bounds__(256, 1)
void prep_kernel(const float* __restrict__ x,
                 const float* __restrict__ W,
                 const float* __restrict__ alphas,
                 const float* __restrict__ v,
                 const int*   __restrict__ alpha_int,
                 unsigned*    __restrict__ ub_g,
                 float*       __restrict__ ig_g)
{
    const int tid  = threadIdx.x;
    const int bid  = blockIdx.x;
    const int wave = tid >> 6;
    const int lane = tid & 63;
    const int r0   = bid * 8 + wave * 2;

    __shared__ __align__(16) float x_tile[8][HDIM];   // 64 KB

    const int ai = alpha_int[0];
    float a[BBASIS];
    float mx = -1e30f;
    #pragma unroll
    for (int b = 0; b < BBASIS; ++b) { a[b] = alphas[ai * BBASIS + b]; mx = fmaxf(mx, a[b]); }
    float ssum = 0.f;
    #pragma unroll
    for (int b = 0; b < BBASIS; ++b) { a[b] = expf(a[b] - mx); ssum += a[b]; }
    const float inv_s = 1.f / ssum;

    {   // u rows r0, r0+1 -> bf16 pairs
        float acc[2][8][4];
        #pragma unroll
        for (int q = 0; q < 2; ++q)
            #pragma unroll
            for (int k = 0; k < 8; ++k)
                #pragma unroll
                for (int i = 0; i < 4; ++i) acc[q][k][i] = 0.f;

        for (int b = 0; b < BBASIS; ++b) {
            const float ab = a[b] * inv_s;
            #pragma unroll
            for (int q = 0; q < 2; ++q) {
                const f32x4* wrow = (const f32x4*)(W + ((size_t)b * HDIM + (size_t)(r0 + q)) * HDIM);
                #pragma unroll
                for (int k = 0; k < 8; ++k) {
                    f32x4 w4 = wrow[lane + 64 * k];
                    acc[q][k][0] += ab * w4.x;
                    acc[q][k][1] += ab * w4.y;
                    acc[q][k][2] += ab * w4.z;
                    acc[q][k][3] += ab * w4.w;
                }
            }
        }
        #pragma unroll
        for (int q = 0; q < 2; ++q) {
            unsigned* ubrow = ub_g + (size_t)(r0 + q) * 1024;
            #pragma unroll
            for (int k = 0; k < 8; ++k) {
                u32x2 p;
                p.x = bf16rne(acc[q][k][0]) | (bf16rne(acc[q][k][1]) << 16);
                p.y = bf16rne(acc[q][k][2]) | (bf16rne(acc[q][k][3]) << 16);
                *(u32x2*)(ubrow + 128 * k + 2 * lane) = p;
            }
        }
    }

    {   // igates rows r0, r0+1
        float vr[2][8][4];
        #pragma unroll
        for (int q = 0; q < 2; ++q) {
            const f32x4* vrow = (const f32x4*)(v + (size_t)(r0 + q) * HDIM);
            #pragma unroll
            for (int k = 0; k < 8; ++k) {
                f32x4 t4 = vrow[lane + 64 * k];
                vr[q][k][0] = t4.x; vr[q][k][1] = t4.y; vr[q][k][2] = t4.z; vr[q][k][3] = t4.w;
            }
        }
        for (int tb = 0; tb < TSTEPS; tb += 8) {
            #pragma unroll
            for (int j = 0; j < 8; ++j) {
                const f32x4* xt4 = (const f32x4*)(x + (size_t)(tb + j) * HDIM);
                #pragma unroll
                for (int c = 0; c < 2; ++c)
                    ((f32x4*)x_tile[j])[tid + 256 * c] = xt4[tid + 256 * c];
            }
            __syncthreads();
            #pragma unroll
            for (int j = 0; j < 8; ++j) {
                float acc0 = 0.f, acc1 = 0.f;
                #pragma unroll
                for (int k = 0; k < 8; ++k) {
                    const f32x4 x4 = ((const f32x4*)x_tile[j])[lane + 64 * k];
                    acc0 += vr[0][k][0]*x4.x + vr[0][k][1]*x4.y + vr[0][k][2]*x4.z + vr[0][k][3]*x4.w;
                    acc1 += vr[1][k][0]*x4.x + vr[1][k][1]*x4.y + vr[1][k][2]*x4.z + vr[1][k][3]*x4.w;
                }
                #pragma unroll
                for (int off = 32; off > 0; off >>= 1) {
                    acc0 += __shfl_xor(acc0, off, 64);
                    acc1 += __shfl_xor(acc1, off, 64);
                }
                if (lane == 0)
                    *(float2*)&ig_g[(size_t)(tb + j) * HDIM + r0] = make_float2(acc0, acc1);
            }
            __syncthreads();
        }
    }
}

// =====================================================================
// ATTEMPT: single-XCD scan, watchdogged. ctrl: [0..7] claim counters,
// [8] winner (xcd+1), [9] abort flag, [10] done counter.
// On any cap/abort: block-uniform return; fallback kernel redoes the scan.
// =====================================================================
__global__ __launch_bounds__(512, 2)
void scan_kernel(const float* __restrict__ bias,
                 const float* __restrict__ fc_w,
                 const float* __restrict__ fc_b,
                 float*       __restrict__ out,
                 const unsigned* __restrict__ ub_g,
                 const float* __restrict__ ig_g,
                 unsigned*    __restrict__ ctrl,
                 float*       __restrict__ ring)     // [RING_D][2048], zeroed
{
    const int tid  = threadIdx.x;
    const int wave = tid >> 6;
    const int lane = tid & 63;

    __shared__ int s_part, s_chunk;
    __shared__ volatile int s_abort;
    if (tid == 0) {
        s_abort = 0;
        unsigned xcc;
        asm volatile("s_getreg_b32 %0, hwreg(HW_REG_XCC_ID)" : "=s"(xcc));
        xcc &= 7u;
        unsigned tk = __hip_atomic_fetch_add(&ctrl[xcc], 1u,
                                             __ATOMIC_RELAXED, __HIP_MEMORY_SCOPE_AGENT);
        if (tk == GRP - 1) {
            unsigned exp = 0u;
            __hip_atomic_compare_exchange_strong(&ctrl[8], &exp, xcc + 1u,
                                                 __ATOMIC_RELAXED, __ATOMIC_RELAXED,
                                                 __HIP_MEMORY_SCOPE_AGENT);
        }
        unsigned w = 0, it = 0; int ok = 1;
        for (;;) {
            w = __hip_atomic_load(&ctrl[8], __ATOMIC_RELAXED, __HIP_MEMORY_SCOPE_AGENT);
            if (w) break;
            ++it;
            if (it >= FCAP ||
                ((it & 15u) == 0u &&
                 __hip_atomic_load(&ctrl[9], __ATOMIC_RELAXED, __HIP_MEMORY_SCOPE_AGENT))) {
                ok = 0; break;
            }
            __builtin_amdgcn_s_sleep(8);
        }
        if (!ok) {
            __hip_atomic_store(&ctrl[9], 1u, __ATOMIC_RELAXED, __HIP_MEMORY_SCOPE_AGENT);
            s_part = 0; s_chunk = 0;
        } else {
            s_part  = (w - 1u == xcc) && (tk < (unsigned)GRP);
            s_chunk = (int)tk;
        }
    }
    __syncthreads();
    if (!s_part) return;
    const int chunk = s_chunk;                 // 0..31
    const int r0    = chunk * 64 + wave * 8;   // wave's first of 8 rows

    __shared__ __align__(16) float h_lds[2][HDIM];      // 16 KB
    __shared__ __align__(16) float ig_lds[TSTEPS][64];  // 64 KB

    #pragma unroll
    for (int i = 0; i < 8; ++i) {
        const int c  = tid + 512 * i;          // 0..4095 f32x4 units
        const int t  = c >> 4;
        const int ch = c & 15;
        f32x4 g = *(const f32x4*)&ig_g[(size_t)t * HDIM + chunk * 64 + ch * 4];
        *(f32x4*)&ig_lds[t][ch * 4] = g;
    }

    u32x2 Ub[8][8];                            // 64 rows/block -> 8 rows/wave, bf16 pairs
    #pragma unroll
    for (int q = 0; q < 8; ++q) {
        const unsigned* ubrow = ub_g + (size_t)(r0 + q) * 1024;
        #pragma unroll
        for (int k = 0; k < 8; ++k) {
            asm volatile("global_load_dwordx2 %0, %1, off"
                         : "=&v"(Ub[q][k])
                         : "v"(ubrow + 128 * k + 2 * lane));
        }
    }
    asm volatile("s_waitcnt vmcnt(0)" ::: "memory");
    __builtin_amdgcn_sched_barrier(0);

    float bias8[8];
    #pragma unroll
    for (int q = 0; q < 8; ++q) bias8[q] = bias[r0 + q];

    h_lds[0][tid]        = 0.f;
    h_lds[0][tid + 512]  = 0.f;
    h_lds[0][tid + 1024] = 0.f;
    h_lds[0][tid + 1536] = 0.f;
    __syncthreads();

    int cur = 0;
    for (int t = 0; t < TSTEPS; ++t) {
        float acc[8];
        #pragma unroll
        for (int q = 0; q < 8; ++q) acc[q] = 0.f;
        #pragma unroll
        for (int k = 0; k < 8; ++k) {
            const f32x4 h4 = ((const f32x4*)h_lds[cur])[lane + 64 * k];
            #pragma unroll
            for (int q = 0; q < 8; ++q) {
                const u32x2 up = Ub[q][k];
                const float u0 = __uint_as_float(up.x << 16);
                const float u1 = __uint_as_float(up.x & 0xFFFF0000u);
                const float u2 = __uint_as_float(up.y << 16);
                const float u3 = __uint_as_float(up.y & 0xFFFF0000u);
                acc[q] += u0*h4.x + u1*h4.y + u2*h4.z + u3*h4.w;
            }
        }
        #pragma unroll
        for (int off = 32; off > 0; off >>= 1)
            #pragma unroll
            for (int q = 0; q < 8; ++q)
                acc[q] += __shfl_xor(acc[q], off, 64);

        const int   st     = t + 1;
        const bool  bpos   = ((st >> 2) & 1) != 0;
        const float bias_f = bpos ? 8.0f : -8.0f;
        float* slotbase = ring + (size_t)(st & (RING_D - 1)) * HDIM;

        float hval[8];
        #pragma unroll
        for (int q = 0; q < 8; ++q) {
            const float ig = ig_lds[t][wave * 8 + q];
            hval[q] = tanhf(acc[q] + ig + bias8[q]) + bias_f;
        }
        if (lane < 2) {
            f32x4 hv;
            if (lane == 0) { hv.x = hval[0]; hv.y = hval[1]; hv.z = hval[2]; hv.w = hval[3]; }
            else           { hv.x = hval[4]; hv.y = hval[5]; hv.z = hval[6]; hv.w = hval[7]; }
            store_l2_f4(slotbase + r0 + 4 * lane, hv);
        }

        // watchdogged poll of own 16B chunk (L2-local)
        const float* pp = slotbase + 4 * tid;
        f32x4 hq;
        {
            unsigned it = 0; int fail = 0;
            for (;;) {
                hq = load_l2_f4(pp);
                bool ok = bpos ? ((hq.x >  6.5f) & (hq.y >  6.5f) & (hq.z >  6.5f) & (hq.w >  6.5f))
                               : ((hq.x < -6.5f) & (hq.y < -6.5f) & (hq.z < -6.5f) & (hq.w < -6.5f));
                if (ok) break;
                ++it;
                if (s_abort) { fail = 1; break; }
                if ((it & 63u) == 0u) {
                    if (it >= PCAP ||
                        __hip_atomic_load(&ctrl[9], __ATOMIC_RELAXED, __HIP_MEMORY_SCOPE_AGENT)) {
                        fail = 1; break;
                    }
                }
                __builtin_amdgcn_s_sleep(1);
            }
            if (fail) s_abort = 1;
        }
        const int nxt = cur ^ 1;
        hq.x -= bias_f; hq.y -= bias_f; hq.z -= bias_f; hq.w -= bias_f;
        *(f32x4*)&h_lds[nxt][4 * tid] = hq;
        __syncthreads();
        if (s_abort) {
            if (tid == 0)
                __hip_atomic_store(&ctrl[9], 1u, __ATOMIC_RELAXED, __HIP_MEMORY_SCOPE_AGENT);
            return;
        }
        cur = nxt;
    }

    {   // out = sigmoid(h @ fc_w.T + fc_b), 8 rows per wave
        float acc[8];
        #pragma unroll
        for (int q = 0; q < 8; ++q) acc[q] = 0.f;
        #pragma unroll
        for (int k = 0; k < 8; ++k) {
            const f32x4 h4 = ((const f32x4*)h_lds[cur])[lane + 64 * k];
            #pragma unroll
            for (int q = 0; q < 8; ++q) {
                const f32x4 w4 = ((const f32x4*)(fc_w + (size_t)(r0 + q) * HDIM))[lane + 64 * k];
                acc[q] += w4.x*h4.x + w4.y*h4.y + w4.z*h4.z + w4.w*h4.w;
            }
        }
        #pragma unroll
        for (int off = 32; off > 0; off >>= 1)
            #pragma unroll
            for (int q = 0; q < 8; ++q)
                acc[q] += __shfl_xor(acc[q], off, 64);
        if (lane < 2) {
            f32x4 o4;
            #pragma unroll
            for (int j = 0; j < 4; ++j) {
                const int q = lane * 4 + j;
                const float s = 1.f / (1.f + expf(-(acc[q] + fc_b[r0 + q])));
                if (j == 0) o4.x = s; else if (j == 1) o4.y = s;
                else if (j == 2) o4.z = s; else o4.w = s;
            }
            *(f32x4*)&out[r0 + 4 * lane] = o4;
        }
    }
    asm volatile("s_waitcnt vmcnt(0)" ::: "memory");
    __syncthreads();
    if (tid == 0)
        __hip_atomic_fetch_add(&ctrl[10], 1u, __ATOMIC_RELAXED, __HIP_MEMORY_SCOPE_AGENT);
}

// =====================================================================
// FALLBACK scan: proven R10 structure (64 blocks, MALL band-ring + 8
// replicas), bf16-u so output is bit-identical to the attempt path.
// Runs only if attempt's done counter != GRP.
// =====================================================================
__global__ __launch_bounds__(512, 2)
void scan_fb_kernel(const float* __restrict__ bias,
                    const float* __restrict__ fc_w,
                    const float* __restrict__ fc_b,
                    float*       __restrict__ out,
                    const unsigned* __restrict__ ub_g,
                    const float* __restrict__ ig_g,
                    unsigned*    __restrict__ ctrl,
                    float*       __restrict__ ring)   // [RING_D][NR][2048], zeroed
{
    const int tid  = threadIdx.x;
    const int bid  = blockIdx.x;
    const int wave = tid >> 6;
    const int lane = tid & 63;
    const int r0   = bid * 32 + wave * 4;

    __shared__ unsigned s_done;
    if (tid == 0)
        s_done = __hip_atomic_load(&ctrl[10], __ATOMIC_RELAXED, __HIP_MEMORY_SCOPE_AGENT);
    __syncthreads();
    if (s_done == (unsigned)GRP) return;      // attempt succeeded

    __shared__ __align__(16) float h_lds[2][HDIM];      // 16 KB
    __shared__ __align__(16) float ig_lds[TSTEPS][32];  // 32 KB

    #pragma unroll
    for (int i = 0; i < 4; ++i) {
        const int c  = tid + 512 * i;
        const int t  = c >> 3;
        const int ch = c & 7;
        f32x4 g = *(const f32x4*)&ig_g[(size_t)t * HDIM + bid * 32 + ch * 4];
        *(f32x4*)&ig_lds[t][ch * 4] = g;
    }

    u32x2 Ub[4][8];
    #pragma unroll
    for (int q = 0; q < 4; ++q) {
        const unsigned* ubrow = ub_g + (size_t)(r0 + q) * 1024;
        #pragma unroll
        for (int k = 0; k < 8; ++k) {
            asm volatile("global_load_dwordx2 %0, %1, off"
                         : "=&v"(Ub[q][k])
                         : "v"(ubrow + 128 * k + 2 * lane));
        }
    }
    asm volatile("s_waitcnt vmcnt(0)" ::: "memory");
    __builtin_amdgcn_sched_barrier(0);

    float bias4[4];
    #pragma unroll
    for (int q = 0; q < 4; ++q) bias4[q] = bias[r0 + q];

    h_lds[0][tid]        = 0.f;
    h_lds[0][tid + 512]  = 0.f;
    h_lds[0][tid + 1024] = 0.f;
    h_lds[0][tid + 1536] = 0.f;
    __syncthreads();

    int cur = 0;
    for (int t = 0; t < TSTEPS; ++t) {
        float acc[4];
        #pragma unroll
        for (int q = 0; q < 4; ++q) acc[q] = 0.f;
        #pragma unroll
        for (int k = 0; k < 8; ++k) {
            const f32x4 h4 = ((const f32x4*)h_lds[cur])[lane + 64 * k];
            #pragma unroll
            for (int q = 0; q < 4; ++q) {
                const u32x2 up = Ub[q][k];
                const float u0 = __uint_as_float(up.x << 16);
                const float u1 = __uint_as_float(up.x & 0xFFFF0000u);
                const float u2 = __uint_as_float(up.y << 16);
                const float u3 = __uint_as_float(up.y & 0xFFFF0000u);
                acc[q] += u0*h4.x + u1*h4.y + u2*h4.z + u3*h4.w;
            }
        }
        #pragma unroll
        for (int off = 32; off > 0; off >>= 1)
            #pragma unroll
            for (int q = 0; q < 4; ++q)
                acc[q] += __shfl_xor(acc[q], off, 64);

        const int   st     = t + 1;
        const bool  bpos   = ((st >> 2) & 1) != 0;
        const float bias_f = bpos ? 8.0f : -8.0f;
        float* slotbase = ring + (size_t)((st & (RING_D - 1)) * NR) * HDIM;

        float hval[4];
        #pragma unroll
        for (int q = 0; q < 4; ++q) {
            const float ig = ig_lds[t][wave * 4 + q];
            hval[q] = tanhf(acc[q] + ig + bias4[q]) + bias_f;
        }
        {
            f32x4 hv; hv.x = hval[0]; hv.y = hval[1]; hv.z = hval[2]; hv.w = hval[3];
            if (lane < NR)
                store_coherent_f4(slotbase + (size_t)lane * HDIM + r0, hv);
        }

        const float* pp = slotbase + (size_t)(bid & (NR - 1)) * HDIM + 4 * tid;
        f32x4 hq = load_coherent_f4(pp);
        if (bpos) {
            while (!((hq.x > 6.5f) & (hq.y > 6.5f) & (hq.z > 6.5f) & (hq.w > 6.5f))) {
                __builtin_amdgcn_s_sleep(1);
                hq = load_coherent_f4(pp);
            }
        } else {
            while (!((hq.x < -6.5f) & (hq.y < -6.5f) & (hq.z < -6.5f) & (hq.w < -6.5f))) {
                __builtin_amdgcn_s_sleep(1);
                hq = load_coherent_f4(pp);
            }
        }
        hq.x -= bias_f; hq.y -= bias_f; hq.z -= bias_f; hq.w -= bias_f;

        const int nxt = cur ^ 1;
        *(f32x4*)&h_lds[nxt][4 * tid] = hq;
        __syncthreads();
        cur = nxt;
    }

    {
        float acc[4];
        #pragma unroll
        for (int q = 0; q < 4; ++q) acc[q] = 0.f;
        #pragma unroll
        for (int k = 0; k < 8; ++k) {
            const f32x4 h4 = ((const f32x4*)h_lds[cur])[lane + 64 * k];
            #pragma unroll
            for (int q = 0; q < 4; ++q) {
                const f32x4 w4 = ((const f32x4*)(fc_w + (size_t)(r0 + q) * HDIM))[lane + 64 * k];
                acc[q] += w4.x*h4.x + w4.y*h4.y + w4.z*h4.z + w4.w*h4.w;
            }
        }
        #pragma unroll
        for (int off = 32; off > 0; off >>= 1)
            #pragma unroll
            for (int q = 0; q < 4; ++q)
                acc[q] += __shfl_xor(acc[q], off, 64);
        if (lane == 0) {
            f32x4 o4;
            o4.x = 1.f / (1.f + expf(-(acc[0] + fc_b[r0 + 0])));
            o4.y = 1.f / (1.f + expf(-(acc[1] + fc_b[r0 + 1])));
            o4.z = 1.f / (1.f + expf(-(acc[2] + fc_b[r0 + 2])));
            o4.w = 1.f / (1.f + expf(-(acc[3] + fc_b[r0 + 3])));
            *(f32x4*)&out[r0] = o4;
        }
    }
}

extern "C" void kernel_launch(void* const* d_in, const int* in_sizes, int n_in,
                              void* d_out, int out_size, void* d_ws, size_t ws_size,
                              hipStream_t stream)
{
    const float* x      = (const float*)d_in[0];
    const float* W      = (const float*)d_in[1];
    const float* alphas = (const float*)d_in[2];
    const float* bias   = (const float*)d_in[3];
    const float* v      = (const float*)d_in[4];
    const float* fc_w   = (const float*)d_in[5];
    const float* fc_b   = (const float*)d_in[6];
    const int*   ai     = (const int*)d_in[7];
    float* out = (float*)d_out;

    // layout: ctrl @0 (256B) | ringA @4KB (32KB) | ringB @64KB (256KB) |
    //         ig @512KB (2MB) | ub @2.5MB (8MB)
    const size_t RINGA_OFF = 4096;
    const size_t RINGB_OFF = 0x10000;
    const size_t IG_OFF    = 0x80000;
    const size_t UB_OFF    = IG_OFF + 0x200000;
    const size_t UB_BYTES  = (size_t)HDIM * 1024 * sizeof(unsigned);   // 8 MB
    const size_t NEED      = UB_OFF + UB_BYTES;                        // ~10.6 MB

    if (ws_size >= NEED) {
        unsigned* ctrl  = (unsigned*)d_ws;
        float*    ringA = (float*)((char*)d_ws + RINGA_OFF);
        float*    ringB = (float*)((char*)d_ws + RINGB_OFF);
        float*    ig_g  = (float*)((char*)d_ws + IG_OFF);
        unsigned* ub_g  = (unsigned*)((char*)d_ws + UB_OFF);
        // zero ctrl + both rings (0.0 fails both parity bands -> clean start)
        hipMemsetAsync(d_ws, 0, RINGB_OFF + (size_t)RING_D * NR * HDIM * sizeof(float), stream);
        prep_kernel<<<256, 256, 0, stream>>>(x, W, alphas, v, ai, ub_g, ig_g);
        scan_kernel<<<256, 512, 0, stream>>>(bias, fc_w, fc_b, out, ub_g, ig_g, ctrl, ringA);
        scan_fb_kernel<<<64, 512, 0, stream>>>(bias, fc_w, fc_b, out, ub_g, ig_g, ctrl, ringB);
    } else {
        // minimal safe path (should not trigger: ws has been >= 18 MB): run
        // prep+fallback only, using the tail of ws if possible is not safe ->
        // just run fallback structures inside available ws via the same split
        // if it fits nothing, do nothing (harness always provided enough).
        unsigned* ctrl  = (unsigned*)d_ws;
        float*    ringB = (float*)((char*)d_ws + RINGA_OFF);
        float*    ig_g  = (float*)((char*)d_ws + RINGA_OFF + 0x40000);
        unsigned* ub_g  = (unsigned*)((char*)d_ws + RINGA_OFF + 0x240000);
        hipMemsetAsync(d_ws, 0, RINGA_OFF + (size_t)RING_D * NR * HDIM * sizeof(float), stream);
        prep_kernel<<<256, 256, 0, stream>>>(x, W, alphas, v, ai, ub_g, ig_g);
        scan_fb_kernel<<<64, 512, 0, stream>>>(bias, fc_w, fc_b, out, ub_g, ig_g, ctrl, ringB);
    }
}

// Round 14
// 990.738 us; speedup vs baseline: 2.0567x; 2.0567x over previous
//
#include <hip/hip_runtime.h>
#include <math.h>

#define HDIM    2048
#define TSTEPS  256
#define BBASIS  8
#define RING_D  4          // ring depth (slots reused mod 4; safe: readers done at st-2)
#define NR      8          // replicas per slot; block b polls replica b&7

typedef float f32x4 __attribute__((ext_vector_type(4)));

// ---------------- coherent (Infinity-Cache level) ops ----------------
__device__ inline void store_coherent_f4(float* p, f32x4 v) {
    asm volatile("global_store_dwordx4 %0, %1, off sc0 sc1"
                 :: "v"(p), "v"(v) : "memory");
}
__device__ inline f32x4 load_coherent_f4(const float* p) {
    f32x4 a;
    asm volatile("global_load_dwordx4 %0, %1, off sc0 sc1\n\t"
                 "s_waitcnt vmcnt(0)"
                 : "=&v"(a) : "v"(p) : "memory");
    return a;
}

// =====================================================================
// PREP kernel: 256 blocks x 256 threads (unchanged, proven).
// Block b owns rows r = b*8 .. b*8+7; wave w (0..3) owns rows b*8+2w, +1.
// Writes u_g[2048][2048] and ig_g[256][2048]. Plain stores: kernel-boundary
// flush makes them visible to the scan kernel.
// =====================================================================
__global__ __launch_bounds__(256, 1)
void prep_kernel(const float* __restrict__ x,        // [256][2048]
                 const float* __restrict__ W,        // [8][2048][2048]
                 const float* __restrict__ alphas,   // [8][8]
                 const float* __restrict__ v,        // [2048][2048]
                 const int*   __restrict__ alpha_int,
                 float*       __restrict__ u_g,      // [2048][2048]
                 float*       __restrict__ ig_g)     // [256][2048]
{
    const int tid  = threadIdx.x;
    const int bid  = blockIdx.x;
    const int wave = tid >> 6;
    const int lane = tid & 63;
    const int r0   = bid * 8 + wave * 2;     // this wave's two rows

    __shared__ __align__(16) float x_tile[8][HDIM];   // 64 KB

    const int ai = alpha_int[0];
    float a[BBASIS];
    float mx = -1e30f;
    #pragma unroll
    for (int b = 0; b < BBASIS; ++b) { a[b] = alphas[ai * BBASIS + b]; mx = fmaxf(mx, a[b]); }
    float ssum = 0.f;
    #pragma unroll
    for (int b = 0; b < BBASIS; ++b) { a[b] = expf(a[b] - mx); ssum += a[b]; }
    const float inv_s = 1.f / ssum;

    // ---- u rows r0, r0+1 ----
    {
        float acc[2][8][4];
        #pragma unroll
        for (int q = 0; q < 2; ++q)
            #pragma unroll
            for (int k = 0; k < 8; ++k)
                #pragma unroll
                for (int i = 0; i < 4; ++i) acc[q][k][i] = 0.f;

        for (int b = 0; b < BBASIS; ++b) {
            const float ab = a[b] * inv_s;
            #pragma unroll
            for (int q = 0; q < 2; ++q) {
                const f32x4* wrow = (const f32x4*)(W + ((size_t)b * HDIM + (size_t)(r0 + q)) * HDIM);
                #pragma unroll
                for (int k = 0; k < 8; ++k) {
                    f32x4 w4 = wrow[lane + 64 * k];
                    acc[q][k][0] += ab * w4.x;
                    acc[q][k][1] += ab * w4.y;
                    acc[q][k][2] += ab * w4.z;
                    acc[q][k][3] += ab * w4.w;
                }
            }
        }
        #pragma unroll
        for (int q = 0; q < 2; ++q) {
            f32x4* urow = (f32x4*)(u_g + (size_t)(r0 + q) * HDIM);
            #pragma unroll
            for (int k = 0; k < 8; ++k) {
                f32x4 w4;
                w4.x = acc[q][k][0]; w4.y = acc[q][k][1];
                w4.z = acc[q][k][2]; w4.w = acc[q][k][3];
                urow[lane + 64 * k] = w4;
            }
        }
    }

    // ---- igates rows r0, r0+1 over all t ----
    {
        float vr[2][8][4];
        #pragma unroll
        for (int q = 0; q < 2; ++q) {
            const f32x4* vrow = (const f32x4*)(v + (size_t)(r0 + q) * HDIM);
            #pragma unroll
            for (int k = 0; k < 8; ++k) {
                f32x4 t4 = vrow[lane + 64 * k];
                vr[q][k][0] = t4.x; vr[q][k][1] = t4.y; vr[q][k][2] = t4.z; vr[q][k][3] = t4.w;
            }
        }
        for (int tb = 0; tb < TSTEPS; tb += 8) {
            #pragma unroll
            for (int j = 0; j < 8; ++j) {
                const f32x4* xt4 = (const f32x4*)(x + (size_t)(tb + j) * HDIM);
                #pragma unroll
                for (int c = 0; c < 2; ++c)
                    ((f32x4*)x_tile[j])[tid + 256 * c] = xt4[tid + 256 * c];
            }
            __syncthreads();
            #pragma unroll
            for (int j = 0; j < 8; ++j) {
                float acc0 = 0.f, acc1 = 0.f;
                #pragma unroll
                for (int k = 0; k < 8; ++k) {
                    const f32x4 x4 = ((const f32x4*)x_tile[j])[lane + 64 * k];
                    acc0 += vr[0][k][0]*x4.x + vr[0][k][1]*x4.y + vr[0][k][2]*x4.z + vr[0][k][3]*x4.w;
                    acc1 += vr[1][k][0]*x4.x + vr[1][k][1]*x4.y + vr[1][k][2]*x4.z + vr[1][k][3]*x4.w;
                }
                #pragma unroll
                for (int off = 32; off > 0; off >>= 1) {
                    acc0 += __shfl_xor(acc0, off, 64);
                    acc1 += __shfl_xor(acc1, off, 64);
                }
                if (lane == 0)
                    *(float2*)&ig_g[(size_t)(tb + j) * HDIM + r0] = make_float2(acc0, acc1);
            }
            __syncthreads();
        }
    }
}

// =====================================================================
// SCAN kernel (R14): R10 base + two isolated deltas:
//  (1) busy-spin polls (no s_sleep) -- tests DVFS clock-droop theory and
//      removes detect quantization.
//  (2) t=0 exchange skipped: h1 = tanh(ig0 + bias) computed locally by
//      every block (h0 = 0, no matvec needed) -> 255 exchanges, not 256.
// Everything else identical to the proven 836us R10 scan.
// =====================================================================
__global__ __launch_bounds__(512, 2)
void scan_kernel(const float* __restrict__ bias,
                 const float* __restrict__ fc_w,
                 const float* __restrict__ fc_b,
                 float*       __restrict__ out,
                 const float* __restrict__ u_g,      // [2048][2048]
                 const float* __restrict__ ig_g,     // [256][2048]
                 float*       __restrict__ ring)     // [RING_D][NR][2048], zeroed
{
    const int tid  = threadIdx.x;
    const int bid  = blockIdx.x;
    const int wave = tid >> 6;
    const int lane = tid & 63;
    const int r0   = bid * 32 + wave * 4;

    __shared__ __align__(16) float h_lds[2][HDIM];      // 16 KB
    __shared__ __align__(16) float ig_lds[TSTEPS][32];  // 32 KB

    // ---- stage this block's igates column [t][bid*32 .. +32] into LDS ----
    #pragma unroll
    for (int i = 0; i < 4; ++i) {
        const int c  = tid + 512 * i;        // 0..2047
        const int t  = c >> 3;
        const int ch = c & 7;
        f32x4 g = *(const f32x4*)&ig_g[(size_t)t * HDIM + bid * 32 + ch * 4];
        *(f32x4*)&ig_lds[t][ch * 4] = g;
    }

    // ---- u rows r0..r0+3 -> registers via asm loads (non-rematerializable) ----
    f32x4 U[4][8];
    #pragma unroll
    for (int q = 0; q < 4; ++q) {
        const float* urow = u_g + (size_t)(r0 + q) * HDIM;
        #pragma unroll
        for (int k = 0; k < 8; ++k) {
            asm volatile("global_load_dwordx4 %0, %1, off"
                         : "=&v"(U[q][k])
                         : "v"(urow + (size_t)(lane + 64 * k) * 4));
        }
    }
    asm volatile("s_waitcnt vmcnt(0)" ::: "memory");
    __builtin_amdgcn_sched_barrier(0);   // rule #18: no reg-only hoisting past the wait

    float bias4[4];
    #pragma unroll
    for (int q = 0; q < 4; ++q) bias4[q] = bias[r0 + q];

    // ---- h1 = tanh(ig0 + bias) computed locally (h0 = 0): no exchange ----
    #pragma unroll
    for (int j = 0; j < 4; ++j) {
        const int idx = tid + 512 * j;
        h_lds[0][idx] = tanhf(ig_g[idx] + bias[idx]);
    }
    __syncthreads();   // also drains lgkm for ig_lds stores

    // ---- sequential scan: t = 1..255, exchange h_{t+1} (st = 2..256) ----
    int cur = 0;
    for (int t = 1; t < TSTEPS; ++t) {
        float acc0 = 0.f, acc1 = 0.f, acc2 = 0.f, acc3 = 0.f;
        #pragma unroll
        for (int k = 0; k < 8; ++k) {
            const f32x4 h4 = ((const f32x4*)h_lds[cur])[lane + 64 * k];
            acc0 += U[0][k].x*h4.x + U[0][k].y*h4.y + U[0][k].z*h4.z + U[0][k].w*h4.w;
            acc1 += U[1][k].x*h4.x + U[1][k].y*h4.y + U[1][k].z*h4.z + U[1][k].w*h4.w;
            acc2 += U[2][k].x*h4.x + U[2][k].y*h4.y + U[2][k].z*h4.z + U[2][k].w*h4.w;
            acc3 += U[3][k].x*h4.x + U[3][k].y*h4.y + U[3][k].z*h4.z + U[3][k].w*h4.w;
        }
        #pragma unroll
        for (int off = 32; off > 0; off >>= 1) {
            acc0 += __shfl_xor(acc0, off, 64);   // butterfly: sums end in ALL lanes
            acc1 += __shfl_xor(acc1, off, 64);
            acc2 += __shfl_xor(acc2, off, 64);
            acc3 += __shfl_xor(acc3, off, 64);
        }
        const int   st     = t + 1;
        const float bias_f = ((st >> 2) & 1) ? 8.0f : -8.0f;   // parity band tag
        const bool  bpos   = bias_f > 0.0f;
        float* slotbase = ring + (size_t)((st & (RING_D - 1)) * NR) * HDIM;

        // all lanes compute identical tanh+bias; lanes 0..7 store the 8 replicas
        const f32x4 ig4 = *(const f32x4*)&ig_lds[t][wave * 4];
        f32x4 hv;
        hv.x = tanhf(acc0 + ig4.x + bias4[0]) + bias_f;
        hv.y = tanhf(acc1 + ig4.y + bias4[1]) + bias_f;
        hv.z = tanhf(acc2 + ig4.z + bias4[2]) + bias_f;
        hv.w = tanhf(acc3 + ig4.w + bias4[3]) + bias_f;
        if (lane < NR)
            store_coherent_f4(slotbase + (size_t)lane * HDIM + r0, hv);

        // busy-spin poll of own 16B chunk of own replica (no s_sleep)
        const float* pp = slotbase + (size_t)(bid & (NR - 1)) * HDIM + 4 * tid;
        f32x4 hq = load_coherent_f4(pp);
        if (bpos) {
            while (!((hq.x > 6.5f) & (hq.y > 6.5f) & (hq.z > 6.5f) & (hq.w > 6.5f)))
                hq = load_coherent_f4(pp);
        } else {
            while (!((hq.x < -6.5f) & (hq.y < -6.5f) & (hq.z < -6.5f) & (hq.w < -6.5f)))
                hq = load_coherent_f4(pp);
        }
        hq.x -= bias_f; hq.y -= bias_f; hq.z -= bias_f; hq.w -= bias_f;  // exact

        const int nxt = cur ^ 1;
        *(f32x4*)&h_lds[nxt][4 * tid] = hq;
        __syncthreads();
        cur = nxt;
    }

    // ---- out = sigmoid(h @ fc_w.T + fc_b), 4 rows per wave ----
    {
        float acc0 = 0.f, acc1 = 0.f, acc2 = 0.f, acc3 = 0.f;
        const f32x4* f0 = (const f32x4*)(fc_w + (size_t)(r0 + 0) * HDIM);
        const f32x4* f1 = (const f32x4*)(fc_w + (size_t)(r0 + 1) * HDIM);
        const f32x4* f2 = (const f32x4*)(fc_w + (size_t)(r0 + 2) * HDIM);
        const f32x4* f3 = (const f32x4*)(fc_w + (size_t)(r0 + 3) * HDIM);
        #pragma unroll
        for (int k = 0; k < 8; ++k) {
            const f32x4 h4 = ((const f32x4*)h_lds[cur])[lane + 64 * k];
            f32x4 w0 = f0[lane + 64 * k];
            f32x4 w1 = f1[lane + 64 * k];
            f32x4 w2 = f2[lane + 64 * k];
            f32x4 w3 = f3[lane + 64 * k];
            acc0 += w0.x*h4.x + w0.y*h4.y + w0.z*h4.z + w0.w*h4.w;
            acc1 += w1.x*h4.x + w1.y*h4.y + w1.z*h4.z + w1.w*h4.w;
            acc2 += w2.x*h4.x + w2.y*h4.y + w2.z*h4.z + w2.w*h4.w;
            acc3 += w3.x*h4.x + w3.y*h4.y + w3.z*h4.z + w3.w*h4.w;
        }
        #pragma unroll
        for (int off = 32; off > 0; off >>= 1) {
            acc0 += __shfl_xor(acc0, off, 64);
            acc1 += __shfl_xor(acc1, off, 64);
            acc2 += __shfl_xor(acc2, off, 64);
            acc3 += __shfl_xor(acc3, off, 64);
        }
        if (lane == 0) {
            f32x4 o4;
            o4.x = 1.f / (1.f + expf(-(acc0 + fc_b[r0 + 0])));
            o4.y = 1.f / (1.f + expf(-(acc1 + fc_b[r0 + 1])));
            o4.z = 1.f / (1.f + expf(-(acc2 + fc_b[r0 + 2])));
            o4.w = 1.f / (1.f + expf(-(acc3 + fc_b[r0 + 3])));
            *(f32x4*)&out[r0] = o4;
        }
    }
}

// =====================================================================
// FALLBACK: R5-style single kernel (sentinel-poll, fresh slots), f32.
// Only used if ws_size is too small (never observed).
// =====================================================================
__global__ __launch_bounds__(512, 1)
void elman_scan_self(const float* __restrict__ x,
                     const float* __restrict__ W,
                     const float* __restrict__ alphas,
                     const float* __restrict__ bias,
                     const float* __restrict__ v,
                     const float* __restrict__ fc_w,
                     const float* __restrict__ fc_b,
                     const int*   __restrict__ alpha_int,
                     float*       __restrict__ out,
                     float*       __restrict__ hbuf)
{
    const int tid  = threadIdx.x;
    const int bid  = blockIdx.x;
    const int wave = tid >> 6;
    const int lane = tid & 63;
    const int r0   = bid * 32 + wave * 4;

    __shared__ __align__(16) float x_tile[8][HDIM];
    __shared__ __align__(16) float ig_lds[TSTEPS][32];
    __shared__ __align__(16) float h_lds[2][HDIM];

    const int ai = alpha_int[0];
    float a[BBASIS];
    float mx = -1e30f;
    #pragma unroll
    for (int b = 0; b < BBASIS; ++b) { a[b] = alphas[ai * BBASIS + b]; mx = fmaxf(mx, a[b]); }
    float ssum = 0.f;
    #pragma unroll
    for (int b = 0; b < BBASIS; ++b) { a[b] = expf(a[b] - mx); ssum += a[b]; }
    const float inv_s = 1.f / ssum;

    {
        float vr[4][8][4];
        #pragma unroll
        for (int q = 0; q < 4; ++q) {
            const f32x4* vrow = (const f32x4*)(v + (size_t)(r0 + q) * HDIM);
            #pragma unroll
            for (int k = 0; k < 8; ++k) {
                f32x4 t4 = vrow[lane + 64 * k];
                vr[q][k][0] = t4.x; vr[q][k][1] = t4.y; vr[q][k][2] = t4.z; vr[q][k][3] = t4.w;
            }
        }
        for (int tb = 0; tb < TSTEPS; tb += 8) {
            #pragma unroll
            for (int j = 0; j < 8; ++j)
                *(f32x4*)&x_tile[j][4 * tid] =
                    *(const f32x4*)&x[(size_t)(tb + j) * HDIM + 4 * tid];
            __syncthreads();
            #pragma unroll
            for (int j = 0; j < 8; ++j) {
                float acc0 = 0.f, acc1 = 0.f, acc2 = 0.f, acc3 = 0.f;
                #pragma unroll
                for (int k = 0; k < 8; ++k) {
                    const f32x4 x4 = ((const f32x4*)x_tile[j])[lane + 64 * k];
                    acc0 += vr[0][k][0]*x4.x + vr[0][k][1]*x4.y + vr[0][k][2]*x4.z + vr[0][k][3]*x4.w;
                    acc1 += vr[1][k][0]*x4.x + vr[1][k][1]*x4.y + vr[1][k][2]*x4.z + vr[1][k][3]*x4.w;
                    acc2 += vr[2][k][0]*x4.x + vr[2][k][1]*x4.y + vr[2][k][2]*x4.z + vr[2][k][3]*x4.w;
                    acc3 += vr[3][k][0]*x4.x + vr[3][k][1]*x4.y + vr[3][k][2]*x4.z + vr[3][k][3]*x4.w;
                }
                #pragma unroll
                for (int off = 32; off > 0; off >>= 1) {
                    acc0 += __shfl_xor(acc0, off, 64);
                    acc1 += __shfl_xor(acc1, off, 64);
                    acc2 += __shfl_xor(acc2, off, 64);
                    acc3 += __shfl_xor(acc3, off, 64);
                }
                if (lane == 0) {
                    f32x4 ig4; ig4.x = acc0; ig4.y = acc1; ig4.z = acc2; ig4.w = acc3;
                    *(f32x4*)&ig_lds[tb + j][wave * 4] = ig4;
                }
            }
            __syncthreads();
        }
    }

    float u_reg[4][8][4];
    #pragma unroll
    for (int q = 0; q < 4; ++q)
        #pragma unroll
        for (int k = 0; k < 8; ++k)
            #pragma unroll
            for (int i = 0; i < 4; ++i) u_reg[q][k][i] = 0.f;

    for (int b = 0; b < BBASIS; ++b) {
        const float ab = a[b] * inv_s;
        #pragma unroll
        for (int q = 0; q < 4; ++q) {
            const f32x4* wrow = (const f32x4*)(W + ((size_t)b * HDIM + (size_t)(r0 + q)) * HDIM);
            #pragma unroll
            for (int k = 0; k < 8; ++k) {
                f32x4 w4 = wrow[lane + 64 * k];
                u_reg[q][k][0] += ab * w4.x;
                u_reg[q][k][1] += ab * w4.y;
                u_reg[q][k][2] += ab * w4.z;
                u_reg[q][k][3] += ab * w4.w;
            }
        }
    }
    float bias4[4];
    #pragma unroll
    for (int q = 0; q < 4; ++q) bias4[q] = bias[r0 + q];

    h_lds[0][tid] = 0.f; h_lds[0][tid + 512] = 0.f;
    h_lds[0][tid + 1024] = 0.f; h_lds[0][tid + 1536] = 0.f;
    __syncthreads();

    int cur = 0;
    for (int t = 0; t < TSTEPS; ++t) {
        float acc0 = 0.f, acc1 = 0.f, acc2 = 0.f, acc3 = 0.f;
        #pragma unroll
        for (int k = 0; k < 8; ++k) {
            const f32x4 h4 = ((const f32x4*)h_lds[cur])[lane + 64 * k];
            acc0 += u_reg[0][k][0]*h4.x + u_reg[0][k][1]*h4.y + u_reg[0][k][2]*h4.z + u_reg[0][k][3]*h4.w;
            acc1 += u_reg[1][k][0]*h4.x + u_reg[1][k][1]*h4.y + u_reg[1][k][2]*h4.z + u_reg[1][k][3]*h4.w;
            acc2 += u_reg[2][k][0]*h4.x + u_reg[2][k][1]*h4.y + u_reg[2][k][2]*h4.z + u_reg[2][k][3]*h4.w;
            acc3 += u_reg[3][k][0]*h4.x + u_reg[3][k][1]*h4.y + u_reg[3][k][2]*h4.z + u_reg[3][k][3]*h4.w;
        }
        #pragma unroll
        for (int off = 32; off > 0; off >>= 1) {
            acc0 += __shfl_xor(acc0, off, 64);
            acc1 += __shfl_xor(acc1, off, 64);
            acc2 += __shfl_xor(acc2, off, 64);
            acc3 += __shfl_xor(acc3, off, 64);
        }
        float* hg = hbuf + (size_t)(t + 1) * HDIM;
        if (lane == 0) {
            const f32x4 ig4 = *(const f32x4*)&ig_lds[t][wave * 4];
            f32x4 hv;
            hv.x = tanhf(acc0 + ig4.x + bias4[0]);
            hv.y = tanhf(acc1 + ig4.y + bias4[1]);
            hv.z = tanhf(acc2 + ig4.z + bias4[2]);
            hv.w = tanhf(acc3 + ig4.w + bias4[3]);
            store_coherent_f4(hg + r0, hv);
        }
        const float* pp = hg + 4 * tid;
        f32x4 hq = load_coherent_f4(pp);
        const unsigned s = 0xFFFFFFFFu;
        while ((__float_as_uint(hq.x) == s) | (__float_as_uint(hq.y) == s) |
               (__float_as_uint(hq.z) == s) | (__float_as_uint(hq.w) == s)) {
            __builtin_amdgcn_s_sleep(1);
            hq = load_coherent_f4(pp);
        }
        const int nxt = cur ^ 1;
        *(f32x4*)&h_lds[nxt][4 * tid] = hq;
        __syncthreads();
        cur = nxt;
    }

    {
        float acc0 = 0.f, acc1 = 0.f, acc2 = 0.f, acc3 = 0.f;
        const f32x4* f0 = (const f32x4*)(fc_w + (size_t)(r0 + 0) * HDIM);
        const f32x4* f1 = (const f32x4*)(fc_w + (size_t)(r0 + 1) * HDIM);
        const f32x4* f2 = (const f32x4*)(fc_w + (size_t)(r0 + 2) * HDIM);
        const f32x4* f3 = (const f32x4*)(fc_w + (size_t)(r0 + 3) * HDIM);
        #pragma unroll
        for (int k = 0; k < 8; ++k) {
            const f32x4 h4 = ((const f32x4*)h_lds[cur])[lane + 64 * k];
            f32x4 w0 = f0[lane + 64 * k];
            f32x4 w1 = f1[lane + 64 * k];
            f32x4 w2 = f2[lane + 64 * k];
            f32x4 w3 = f3[lane + 64 * k];
            acc0 += w0.x*h4.x + w0.y*h4.y + w0.z*h4.z + w0.w*h4.w;
            acc1 += w1.x*h4.x + w1.y*h4.y + w1.z*h4.z + w1.w*h4.w;
            acc2 += w2.x*h4.x + w2.y*h4.y + w2.z*h4.z + w2.w*h4.w;
            acc3 += w3.x*h4.x + w3.y*h4.y + w3.z*h4.z + w3.w*h4.w;
        }
        #pragma unroll
        for (int off = 32; off > 0; off >>= 1) {
            acc0 += __shfl_xor(acc0, off, 64);
            acc1 += __shfl_xor(acc1, off, 64);
            acc2 += __shfl_xor(acc2, off, 64);
            acc3 += __shfl_xor(acc3, off, 64);
        }
        if (lane == 0) {
            f32x4 o4;
            o4.x = 1.f / (1.f + expf(-(acc0 + fc_b[r0 + 0])));
            o4.y = 1.f / (1.f + expf(-(acc1 + fc_b[r0 + 1])));
            o4.z = 1.f / (1.f + expf(-(acc2 + fc_b[r0 + 2])));
            o4.w = 1.f / (1.f + expf(-(acc3 + fc_b[r0 + 3])));
            *(f32x4*)&out[r0] = o4;
        }
    }
}

extern "C" void kernel_launch(void* const* d_in, const int* in_sizes, int n_in,
                              void* d_out, int out_size, void* d_ws, size_t ws_size,
                              hipStream_t stream)
{
    const float* x      = (const float*)d_in[0];
    const float* W      = (const float*)d_in[1];
    const float* alphas = (const float*)d_in[2];
    const float* bias   = (const float*)d_in[3];
    const float* v      = (const float*)d_in[4];
    const float* fc_w   = (const float*)d_in[5];
    const float* fc_b   = (const float*)d_in[6];
    const int*   ai     = (const int*)d_in[7];
    float* out = (float*)d_out;

    // workspace layout (split path)
    const size_t RING_BYTES = (size_t)RING_D * NR * HDIM * sizeof(float);  // 256 KB
    const size_t IG_OFF     = 0x80000;                                      // 512 KB
    const size_t U_OFF      = IG_OFF + 0x200000;                            // +2 MB
    const size_t U_BYTES    = (size_t)HDIM * HDIM * sizeof(float);          // 16 MB
    const size_t NEED       = U_OFF + U_BYTES;                              // ~18.5 MB

    if (ws_size >= NEED) {
        float* ring = (float*)d_ws;
        float* ig_g = (float*)((char*)d_ws + IG_OFF);
        float* u_g  = (float*)((char*)d_ws + U_OFF);
        // zero the ring each launch: 0.0 fails both parity bands -> clean start
        // (intra-launch reuse is protected by the alternating band tag).
        hipMemsetAsync(d_ws, 0, RING_BYTES, stream);
        prep_kernel<<<256, 256, 0, stream>>>(x, W, alphas, v, ai, u_g, ig_g);
        scan_kernel<<<64, 512, 0, stream>>>(bias, fc_w, fc_b, out, u_g, ig_g, (float*)ring);
    } else {
        // fallback: R5 single kernel with sentinel slots
        float* hbuf = (float*)d_ws;
        const size_t hbuf_bytes = (size_t)(TSTEPS + 1) * HDIM * sizeof(float);
        hipMemsetAsync(d_ws, 0xFF, hbuf_bytes, stream);
        elman_scan_self<<<64, 512, 0, stream>>>(x, W, alphas, bias, v, fc_w, fc_b,
                                                ai, out, hbuf);
    }
}